// Round 14
// baseline (455.125 us; speedup 1.0000x reference)
//
#include <hip/hip_runtime.h>
#include <math.h>

#define NPTS 40000
#define KNBR 16
#define BN_EPS 1e-5f

typedef __attribute__((ext_vector_type(8))) short v8s;
typedef __attribute__((ext_vector_type(4))) float f32x4;
typedef unsigned short us;

__device__ __forceinline__ us f2bf(float f) {
    union { float f; unsigned int u; } c; c.f = f;
    unsigned int u = c.u + 0x7fffu + ((c.u >> 16) & 1u);   // RNE
    return (us)(u >> 16);
}
__device__ __forceinline__ float bflo(unsigned int u) {
    union { unsigned int u; float f; } c; c.u = u << 16; return c.f;
}
__device__ __forceinline__ float bfhi(unsigned int u) {
    union { unsigned int u; float f; } c; c.u = u & 0xffff0000u; return c.f;
}
__device__ __forceinline__ float bf2f(us u) {
    union { unsigned int u; float f; } c; c.u = ((unsigned int)u) << 16; return c.f;
}

// ---------------------------------------------------------------------------
// K1: per-point normals + B1[j][64] = [pos_j, normal_j] @ W1[0:6] + b1 (bf16)
// ---------------------------------------------------------------------------
__global__ __launch_bounds__(256, 4)
void k1_b1(const float* __restrict__ pos, const int* __restrict__ nbr,
           const float* __restrict__ W1, const float* __restrict__ b1,
           us* __restrict__ B1) {
    int p = blockIdx.x * 4 + (threadIdx.x >> 6);
    int k = threadIdx.x & 63;
    float px = pos[p * 3 + 0], py = pos[p * 3 + 1], pz = pos[p * 3 + 2];
    int n0 = nbr[p * KNBR + 0], n1 = nbr[p * KNBR + 1];
    float ax = pos[n0 * 3 + 0] - px, ay = pos[n0 * 3 + 1] - py, az = pos[n0 * 3 + 2] - pz;
    float bx = pos[n1 * 3 + 0] - px, by = pos[n1 * 3 + 1] - py, bz = pos[n1 * 3 + 2] - pz;
    float cx = ay * bz - az * by;
    float cy = az * bx - ax * bz;
    float cz = ax * by - ay * bx;
    float nrm = sqrtf(cx * cx + cy * cy + cz * cz);
    float inv = 1.0f / fmaxf(nrm, 1e-12f);
    float ux, uy, uz;
    if (nrm > 0.0f) { ux = cx * inv; uy = cy * inv; uz = cz * inv; }
    else            { ux = 0.0f;     uy = 0.0f;     uz = 1.0f;     }
    float acc = b1[k];
    acc = fmaf(px, W1[0 * 64 + k], acc);
    acc = fmaf(py, W1[1 * 64 + k], acc);
    acc = fmaf(pz, W1[2 * 64 + k], acc);
    acc = fmaf(ux, W1[3 * 64 + k], acc);
    acc = fmaf(uy, W1[4 * 64 + k], acc);
    acc = fmaf(uz, W1[5 * 64 + k], acc);
    B1[p * 64 + k] = f2bf(acc);
}

// ---------------------------------------------------------------------------
// K2 (unchanged from R13): conv1 + k3 folded, M=64 tile, self amortized.
// ---------------------------------------------------------------------------
#define PTS2 32
#define NG2 8
__global__ __launch_bounds__(256, 2)
void k2_conv1_mfma(const float* __restrict__ pos, const int* __restrict__ nbr,
                   const us* __restrict__ B1, const float* __restrict__ W1,
                   const float* __restrict__ g1, const float* __restrict__ bt1,
                   const float* __restrict__ m1, const float* __restrict__ v1,
                   const float* __restrict__ W2, const float* __restrict__ b2,
                   const float* __restrict__ W3, const float* __restrict__ b3,
                   us* __restrict__ A2) {
    __shared__ __align__(16) unsigned char Tl[2][64 * 128];
    __shared__ __align__(16) unsigned char Hl[32 * 256];
    __shared__ us Ssb[32 * 128];

    const int tid  = threadIdx.x;
    const int wv   = tid >> 6;
    const int lane = tid & 63;
    const int lgrp = lane >> 4;
    const int lmod = lane & 15;

    v8s Bf2[2][2];
    float b2c[2];
#pragma unroll
    for (int nt = 0; nt < 2; ++nt) {
        const int col = wv * 32 + nt * 16 + lmod;
        b2c[nt] = b2[col];
#pragma unroll
        for (int kt = 0; kt < 2; ++kt)
#pragma unroll
            for (int j = 0; j < 8; ++j)
                Bf2[nt][kt][j] = (short)f2bf(W2[(kt * 32 + lgrp * 8 + j) * 128 + col]);
    }
    const int ch = lane;
    const float w6 = W1[6 * 64 + ch], w7 = W1[7 * 64 + ch], w8 = W1[8 * 64 + ch];
    const float s1 = g1[ch] * rsqrtf(v1[ch] + BN_EPS);
    const float o1 = bt1[ch] - m1[ch] * s1;

    const int base = blockIdx.x * PTS2;

#pragma unroll
    for (int r = 0; r < 8; ++r) {
        const int pl = wv * 8 + r;
        const float bv = bf2f(B1[(size_t)(base + pl) * 64 + ch]);
        const float t = fmaf(fmaxf(bv, 0.f), s1, o1);
        int byte = pl * 128 + ch * 2;
        byte ^= (pl & 7) << 4;
        *(us*)(Tl[0] + byte) = f2bf(t);
    }
    __syncthreads();
    {
        f32x4 accS[2][2];
#pragma unroll
        for (int hf = 0; hf < 2; ++hf)
#pragma unroll
            for (int nt = 0; nt < 2; ++nt) accS[hf][nt] = f32x4{0.f, 0.f, 0.f, 0.f};
#pragma unroll
        for (int hf = 0; hf < 2; ++hf)
#pragma unroll
            for (int kt = 0; kt < 2; ++kt) {
                const int row = hf * 16 + lmod;
                int b0 = row * 128 + kt * 64 + lgrp * 16;
                b0 ^= (row & 7) << 4;
                const v8s a0 = *(const v8s*)(Tl[0] + b0);
#pragma unroll
                for (int nt = 0; nt < 2; ++nt)
                    accS[hf][nt] = __builtin_amdgcn_mfma_f32_16x16x32_bf16(a0, Bf2[nt][kt], accS[hf][nt], 0, 0, 0);
            }
#pragma unroll
        for (int hf = 0; hf < 2; ++hf)
#pragma unroll
            for (int nt = 0; nt < 2; ++nt)
#pragma unroll
                for (int reg = 0; reg < 4; ++reg)
                    Ssb[(hf * 16 + lgrp * 4 + reg) * 128 + wv * 32 + nt * 16 + lmod] =
                        f2bf(accS[hf][nt][reg]);
    }
    __syncthreads();

    {
        const int i0 = base + wv;
        const float cx = pos[i0 * 3 + 0], cy = pos[i0 * 3 + 1], cz = pos[i0 * 3 + 2];
#pragma unroll
        for (int m = 0; m < 16; ++m) {
            int idx = nbr[i0 * KNBR + m];
            idx = __builtin_amdgcn_readfirstlane(idx);
            const float bv = bf2f(B1[(size_t)idx * 64 + ch]);
            const float rx = pos[idx * 3 + 0] - cx;
            const float ry = pos[idx * 3 + 1] - cy;
            const float rz = pos[idx * 3 + 2] - cz;
            float pre = bv;
            pre = fmaf(rx, w6, pre); pre = fmaf(ry, w7, pre); pre = fmaf(rz, w8, pre);
            const float t = fmaf(fmaxf(pre, 0.f), s1, o1);
            const int row = wv * 16 + m;
            int byte = row * 128 + ch * 2;
            byte ^= (row & 7) << 4;
            *(us*)(Tl[0] + byte) = f2bf(t);
        }
    }
    __syncthreads();

    us aN[16];
    int idxN[16];
    float cNx = 0.f, cNy = 0.f, cNz = 0.f;
    for (int g = 0; g < NG2; ++g) {
        const int buf = g & 1;
        if (g < NG2 - 1) {
            const int iN = base + (g + 1) * 4 + wv;
            cNx = pos[iN * 3 + 0]; cNy = pos[iN * 3 + 1]; cNz = pos[iN * 3 + 2];
#pragma unroll
            for (int m = 0; m < 16; ++m) {
                int idx = nbr[iN * KNBR + m];
                idx = __builtin_amdgcn_readfirstlane(idx);
                idxN[m] = idx;
                aN[m] = B1[(size_t)idx * 64 + ch];
            }
        }
#pragma unroll
        for (int rb = 0; rb < 4; ++rb) {
            f32x4 acc[2];
            acc[0] = f32x4{0.f, 0.f, 0.f, 0.f};
            acc[1] = f32x4{0.f, 0.f, 0.f, 0.f};
#pragma unroll
            for (int kt = 0; kt < 2; ++kt) {
                const int row = rb * 16 + lmod;
                int b0 = row * 128 + kt * 64 + lgrp * 16;
                b0 ^= (row & 7) << 4;
                const v8s a0 = *(const v8s*)(Tl[buf] + b0);
#pragma unroll
                for (int nt = 0; nt < 2; ++nt)
                    acc[nt] = __builtin_amdgcn_mfma_f32_16x16x32_bf16(a0, Bf2[nt][kt], acc[nt], 0, 0, 0);
            }
            const int pl = g * 4 + rb;
#pragma unroll
            for (int nt = 0; nt < 2; ++nt) {
                float mv = fmaxf(fmaxf(acc[nt][0], acc[nt][1]),
                                 fmaxf(acc[nt][2], acc[nt][3]));
                mv = fmaxf(mv, __shfl_xor(mv, 16));
                mv = fmaxf(mv, __shfl_xor(mv, 32));
                const float ss = bf2f(Ssb[pl * 128 + wv * 32 + nt * 16 + lmod]);
                const float h = fmaxf(fmaxf(mv, ss) + b2c[nt], 0.f);
                if (lgrp == 0) {
                    int hb = pl * 256 + (wv * 32 + nt * 16 + lmod) * 2;
                    hb ^= (pl & 7) << 4;
                    *(us*)(Hl + hb) = f2bf(h);
                }
            }
        }
        if (g < NG2 - 1) {
#pragma unroll
            for (int m = 0; m < 16; ++m) {
                const int idx = idxN[m];
                const float rx = pos[idx * 3 + 0] - cNx;
                const float ry = pos[idx * 3 + 1] - cNy;
                const float rz = pos[idx * 3 + 2] - cNz;
                float pre = bf2f(aN[m]);
                pre = fmaf(rx, w6, pre); pre = fmaf(ry, w7, pre); pre = fmaf(rz, w8, pre);
                const float t = fmaf(fmaxf(pre, 0.f), s1, o1);
                const int row = wv * 16 + m;
                int byte = row * 128 + ch * 2;
                byte ^= (row & 7) << 4;
                *(us*)(Tl[buf ^ 1] + byte) = f2bf(t);
            }
        }
        __syncthreads();
    }

    v8s Wf3[2][4];
    float b3c[2];
#pragma unroll
    for (int nt = 0; nt < 2; ++nt) {
        const int col = wv * 32 + nt * 16 + lmod;
        b3c[nt] = b3[col];
#pragma unroll
        for (int kt = 0; kt < 4; ++kt)
#pragma unroll
            for (int j = 0; j < 8; ++j)
                Wf3[nt][kt][j] = (short)f2bf(W3[(kt * 32 + lgrp * 8 + j) * 128 + col]);
    }
    f32x4 accA[2][2];
#pragma unroll
    for (int mt = 0; mt < 2; ++mt)
#pragma unroll
        for (int nt = 0; nt < 2; ++nt) accA[mt][nt] = f32x4{0.f, 0.f, 0.f, 0.f};
#pragma unroll
    for (int kt = 0; kt < 4; ++kt) {
#pragma unroll
        for (int mt = 0; mt < 2; ++mt) {
            int ba = (mt * 16 + lmod) * 256 + kt * 64 + lgrp * 16;
            ba ^= (lmod & 7) << 4;
            const v8s aH = *(const v8s*)(Hl + ba);
#pragma unroll
            for (int nt = 0; nt < 2; ++nt)
                accA[mt][nt] = __builtin_amdgcn_mfma_f32_16x16x32_bf16(aH, Wf3[nt][kt], accA[mt][nt], 0, 0, 0);
        }
    }
#pragma unroll
    for (int mt = 0; mt < 2; ++mt)
#pragma unroll
        for (int nt = 0; nt < 2; ++nt)
#pragma unroll
            for (int reg = 0; reg < 4; ++reg) {
                const int row = base + mt * 16 + lgrp * 4 + reg;
                const int col = wv * 32 + nt * 16 + lmod;
                A2[(size_t)row * 128 + col] = f2bf(accA[mt][nt][reg] + b3c[nt]);
            }
}

// ---------------------------------------------------------------------------
// K4a: materialize messages. Barrier-free grid-stride; wave = one message row.
//   T[(p-c0)*16+j][128] = BN(relu(A2[idx] + rel . W3[128:131])) (bf16)
//   Tself[i][128] = BN(relu(A2[i]))  (rel = 0)
// ---------------------------------------------------------------------------
__global__ __launch_bounds__(256, 4)
void k4a_mat(const float* __restrict__ pos, const int* __restrict__ nbr,
             const us* __restrict__ A2, const float* __restrict__ W3,
             const float* __restrict__ g2, const float* __restrict__ bt2,
             const float* __restrict__ m2, const float* __restrict__ v2,
             us* __restrict__ T, us* __restrict__ Tself,
             int c0, int npts) {
    const int lane = threadIdx.x & 63;
    const int gw = blockIdx.x * 4 + (threadIdx.x >> 6);
    const int nw = gridDim.x * 4;
    const int ch0 = lane * 2;
    const float bw0a = W3[128 * 128 + ch0],     bw1a = W3[129 * 128 + ch0],     bw2a = W3[130 * 128 + ch0];
    const float bw0b = W3[128 * 128 + ch0 + 1], bw1b = W3[129 * 128 + ch0 + 1], bw2b = W3[130 * 128 + ch0 + 1];
    const float sa = g2[ch0] * rsqrtf(v2[ch0] + BN_EPS);
    const float oa = bt2[ch0] - m2[ch0] * sa;
    const float sb = g2[ch0 + 1] * rsqrtf(v2[ch0 + 1] + BN_EPS);
    const float ob = bt2[ch0 + 1] - m2[ch0 + 1] * sb;

    const int nrows = npts * 16;
    for (int row = gw; row < nrows; row += nw) {
        const int il = row >> 4, j = row & 15;
        const int i = c0 + il;
        const int idx = nbr[i * KNBR + j];
        const unsigned int a = *(const unsigned int*)&A2[(size_t)idx * 128 + ch0];
        const float rx = pos[idx * 3 + 0] - pos[i * 3 + 0];
        const float ry = pos[idx * 3 + 1] - pos[i * 3 + 1];
        const float rz = pos[idx * 3 + 2] - pos[i * 3 + 2];
        float pa = bflo(a);
        pa = fmaf(rx, bw0a, pa); pa = fmaf(ry, bw1a, pa); pa = fmaf(rz, bw2a, pa);
        float pb = bfhi(a);
        pb = fmaf(rx, bw0b, pb); pb = fmaf(ry, bw1b, pb); pb = fmaf(rz, bw2b, pb);
        const float ta = fmaf(fmaxf(pa, 0.f), sa, oa);
        const float tb = fmaf(fmaxf(pb, 0.f), sb, ob);
        const unsigned int w = (unsigned int)f2bf(ta) | ((unsigned int)f2bf(tb) << 16);
        *(unsigned int*)((unsigned char*)T + (size_t)row * 256 + ch0 * 2) = w;
    }
    for (int p = gw; p < npts; p += nw) {
        const int i = c0 + p;
        const unsigned int a = *(const unsigned int*)&A2[(size_t)i * 128 + ch0];
        const float ta = fmaf(fmaxf(bflo(a), 0.f), sa, oa);
        const float tb = fmaf(fmaxf(bfhi(a), 0.f), sb, ob);
        const unsigned int w = (unsigned int)f2bf(ta) | ((unsigned int)f2bf(tb) << 16);
        *(unsigned int*)((unsigned char*)Tself + (size_t)i * 256 + ch0 * 2) = w;
    }
}

// ---------------------------------------------------------------------------
// K4b: dense GEMM + max + classifier. NO LDS, NO barriers. Block = 4 waves,
// each wave owns 64 W4 cols; block handles 16 points (256 T-rows, read
// straight from global as A-fragments). Self scores via one 16-row MFMA
// block on Tself + __shfl. Partials -> Z; log_softmax in k5.
// ---------------------------------------------------------------------------
__global__ __launch_bounds__(256, 2)
void k4b_gemm(const us* __restrict__ T, const us* __restrict__ Tself,
              const float* __restrict__ W4, const float* __restrict__ b4,
              const float* __restrict__ Wc, float* __restrict__ Z,
              int c0, int npts) {
    const int tid  = threadIdx.x;
    const int wv   = tid >> 6;
    const int lane = tid & 63;
    const int lgrp = lane >> 4;
    const int lmod = lane & 15;

    v8s Bf[4][4];
#pragma unroll
    for (int nt = 0; nt < 4; ++nt) {
        const int col = wv * 64 + nt * 16 + lmod;
#pragma unroll
        for (int kt = 0; kt < 4; ++kt)
#pragma unroll
            for (int j = 0; j < 8; ++j)
                Bf[nt][kt][j] = (short)f2bf(W4[(kt * 32 + lgrp * 8 + j) * 256 + col]);
    }
    float b4c[4];
#pragma unroll
    for (int nt = 0; nt < 4; ++nt) b4c[nt] = b4[wv * 64 + nt * 16 + lmod];

    const int plb = blockIdx.x * 16;            // local point base in chunk
    const unsigned char* Tb = (const unsigned char*)T;
    const unsigned char* Tsb = (const unsigned char*)Tself;

    // ---- self block: rows = points plb..plb+15 ----
    f32x4 sacc[4];
#pragma unroll
    for (int nt = 0; nt < 4; ++nt) sacc[nt] = f32x4{0.f, 0.f, 0.f, 0.f};
#pragma unroll
    for (int kt = 0; kt < 4; ++kt) {
        const v8s a0 = *(const v8s*)(Tsb + (size_t)(c0 + plb + lmod) * 256 + kt * 64 + lgrp * 16);
#pragma unroll
        for (int nt = 0; nt < 4; ++nt)
            sacc[nt] = __builtin_amdgcn_mfma_f32_16x16x32_bf16(a0, Bf[nt][kt], sacc[nt], 0, 0, 0);
    }

    // ---- 16 points: neighbor GEMM + max + self + classifier ----
#pragma unroll
    for (int r = 0; r < 16; ++r) {
        f32x4 acc[4];
#pragma unroll
        for (int nt = 0; nt < 4; ++nt) acc[nt] = f32x4{0.f, 0.f, 0.f, 0.f};
#pragma unroll
        for (int kt = 0; kt < 4; ++kt) {
            const v8s a0 = *(const v8s*)(Tb + (size_t)((plb + r) * 16 + lmod) * 256 + kt * 64 + lgrp * 16);
#pragma unroll
            for (int nt = 0; nt < 4; ++nt)
                acc[nt] = __builtin_amdgcn_mfma_f32_16x16x32_bf16(a0, Bf[nt][kt], acc[nt], 0, 0, 0);
        }
        float part[8];
#pragma unroll
        for (int c = 0; c < 8; ++c) part[c] = 0.f;
#pragma unroll
        for (int nt = 0; nt < 4; ++nt) {
            float mv = fmaxf(fmaxf(acc[nt][0], acc[nt][1]),
                             fmaxf(acc[nt][2], acc[nt][3]));
            mv = fmaxf(mv, __shfl_xor(mv, 16));
            mv = fmaxf(mv, __shfl_xor(mv, 32));
            const float ss = __shfl(sacc[nt][r & 3], (r >> 2) * 16 + lmod);
            const float h = fmaxf(fmaxf(mv, ss) + b4c[nt], 0.f);
            const int col = wv * 64 + nt * 16 + lmod;
            const float4 wc0 = *(const float4*)&Wc[col * 8 + 0];
            const float4 wc1 = *(const float4*)&Wc[col * 8 + 4];
            part[0] = fmaf(h, wc0.x, part[0]); part[1] = fmaf(h, wc0.y, part[1]);
            part[2] = fmaf(h, wc0.z, part[2]); part[3] = fmaf(h, wc0.w, part[3]);
            part[4] = fmaf(h, wc1.x, part[4]); part[5] = fmaf(h, wc1.y, part[5]);
            part[6] = fmaf(h, wc1.z, part[6]); part[7] = fmaf(h, wc1.w, part[7]);
        }
#pragma unroll
        for (int c = 0; c < 8; ++c) {
            part[c] += __shfl_xor(part[c], 1);
            part[c] += __shfl_xor(part[c], 2);
            part[c] += __shfl_xor(part[c], 4);
            part[c] += __shfl_xor(part[c], 8);
        }
        if (lane == 0) {
#pragma unroll
            for (int c = 0; c < 8; ++c)
                Z[(size_t)(c0 + plb + r) * 32 + wv * 8 + c] = part[c];
        }
    }
}

// ---------------------------------------------------------------------------
// K5: out[i] = log_softmax( sum_w Z[i][w] + bc )
// ---------------------------------------------------------------------------
__global__ __launch_bounds__(256, 4)
void k5_softmax(const float* __restrict__ Z, const float* __restrict__ bc,
                float* __restrict__ out) {
    const int i = blockIdx.x * 256 + threadIdx.x;
    if (i >= NPTS) return;
    float z[8];
#pragma unroll
    for (int c = 0; c < 8; ++c) z[c] = bc[c];
#pragma unroll
    for (int w = 0; w < 4; ++w) {
        const float4 a = *(const float4*)&Z[(size_t)i * 32 + w * 8 + 0];
        const float4 b = *(const float4*)&Z[(size_t)i * 32 + w * 8 + 4];
        z[0] += a.x; z[1] += a.y; z[2] += a.z; z[3] += a.w;
        z[4] += b.x; z[5] += b.y; z[6] += b.z; z[7] += b.w;
    }
    float mz = z[0];
#pragma unroll
    for (int c = 1; c < 8; ++c) mz = fmaxf(mz, z[c]);
    float se = 0.f;
#pragma unroll
    for (int c = 0; c < 8; ++c) se += expf(z[c] - mz);
    const float lse = mz + logf(se);
#pragma unroll
    for (int c = 0; c < 8; ++c) out[(size_t)i * 8 + c] = z[c] - lse;
}

extern "C" void kernel_launch(void* const* d_in, const int* in_sizes, int n_in,
                              void* d_out, int out_size, void* d_ws, size_t ws_size,
                              hipStream_t stream) {
    const float* pos = (const float*)d_in[0];
    const int*   nbr = (const int*)d_in[1];
    const float* W1  = (const float*)d_in[2];
    const float* b1  = (const float*)d_in[3];
    const float* g1  = (const float*)d_in[4];
    const float* bt1 = (const float*)d_in[5];
    const float* m1  = (const float*)d_in[6];
    const float* v1  = (const float*)d_in[7];
    const float* W2  = (const float*)d_in[8];
    const float* b2  = (const float*)d_in[9];
    const float* W3  = (const float*)d_in[10];
    const float* b3  = (const float*)d_in[11];
    const float* g2  = (const float*)d_in[12];
    const float* bt2 = (const float*)d_in[13];
    const float* m2  = (const float*)d_in[14];
    const float* v2  = (const float*)d_in[15];
    const float* W4  = (const float*)d_in[16];
    const float* b4  = (const float*)d_in[17];
    const float* Wc  = (const float*)d_in[18];
    const float* bc  = (const float*)d_in[19];
    float* out = (float*)d_out;

    us* B1    = (us*)d_ws;                          // 40000*64*2   =  5.12 MB
    us* A2    = B1 + (size_t)NPTS * 64;             // 40000*128*2  = 10.24 MB
    us* Tself = A2 + (size_t)NPTS * 128;            // 40000*128*2  = 10.24 MB
    float* Z  = (float*)(Tself + (size_t)NPTS * 128); // 40000*32*4 =  5.12 MB
    us* T     = (us*)(Z + (size_t)NPTS * 32);       // chunk*16*128*2

    const size_t fixed = (size_t)NPTS * (64 + 128 + 128) * 2 + (size_t)NPTS * 32 * 4;
    int chunk = 40000;                               // ladder: 40000/20000/8000/4000
    if (fixed + (size_t)chunk * 16 * 256 > ws_size) chunk = 20000;
    if (fixed + (size_t)chunk * 16 * 256 > ws_size) chunk = 8000;
    if (fixed + (size_t)chunk * 16 * 256 > ws_size) chunk = 4000;
    const int nch = NPTS / chunk;

    k1_b1<<<NPTS / 4, 256, 0, stream>>>(pos, nbr, W1, b1, B1);
    k2_conv1_mfma<<<NPTS / PTS2, 256, 0, stream>>>(pos, nbr, B1, W1, g1, bt1, m1, v1,
                                                   W2, b2, W3, b3, A2);
    for (int c = 0; c < nch; ++c) {
        k4a_mat<<<512, 256, 0, stream>>>(pos, nbr, A2, W3, g2, bt2, m2, v2,
                                         T, Tself, c * chunk, chunk);
        k4b_gemm<<<chunk / 16, 256, 0, stream>>>(T, Tself, W4, b4, Wc, Z,
                                                 c * chunk, chunk);
    }
    k5_softmax<<<(NPTS + 255) / 256, 256, 0, stream>>>(Z, bc, out);
}

// Round 15
// 319.342 us; speedup vs baseline: 1.4252x; 1.4252x over previous
//
#include <hip/hip_runtime.h>
#include <math.h>

#define NPTS 40000
#define KNBR 16
#define BN_EPS 1e-5f

typedef __attribute__((ext_vector_type(8))) short v8s;
typedef __attribute__((ext_vector_type(4))) float f32x4;
typedef unsigned short us;

__device__ __forceinline__ us f2bf(float f) {
    union { float f; unsigned int u; } c; c.f = f;
    unsigned int u = c.u + 0x7fffu + ((c.u >> 16) & 1u);   // RNE
    return (us)(u >> 16);
}
__device__ __forceinline__ float bflo(unsigned int u) {
    union { unsigned int u; float f; } c; c.u = u << 16; return c.f;
}
__device__ __forceinline__ float bfhi(unsigned int u) {
    union { unsigned int u; float f; } c; c.u = u & 0xffff0000u; return c.f;
}
__device__ __forceinline__ float bf2f(us u) {
    union { unsigned int u; float f; } c; c.u = ((unsigned int)u) << 16; return c.f;
}

// ---------------------------------------------------------------------------
// K1: per-point normals + B1[j][64] = [pos_j, normal_j] @ W1[0:6] + b1 (bf16)
// ---------------------------------------------------------------------------
__global__ __launch_bounds__(256, 4)
void k1_b1(const float* __restrict__ pos, const int* __restrict__ nbr,
           const float* __restrict__ W1, const float* __restrict__ b1,
           us* __restrict__ B1) {
    int p = blockIdx.x * 4 + (threadIdx.x >> 6);
    int k = threadIdx.x & 63;
    float px = pos[p * 3 + 0], py = pos[p * 3 + 1], pz = pos[p * 3 + 2];
    int n0 = nbr[p * KNBR + 0], n1 = nbr[p * KNBR + 1];
    float ax = pos[n0 * 3 + 0] - px, ay = pos[n0 * 3 + 1] - py, az = pos[n0 * 3 + 2] - pz;
    float bx = pos[n1 * 3 + 0] - px, by = pos[n1 * 3 + 1] - py, bz = pos[n1 * 3 + 2] - pz;
    float cx = ay * bz - az * by;
    float cy = az * bx - ax * bz;
    float cz = ax * by - ay * bx;
    float nrm = sqrtf(cx * cx + cy * cy + cz * cz);
    float inv = 1.0f / fmaxf(nrm, 1e-12f);
    float ux, uy, uz;
    if (nrm > 0.0f) { ux = cx * inv; uy = cy * inv; uz = cz * inv; }
    else            { ux = 0.0f;     uy = 0.0f;     uz = 1.0f;     }
    float acc = b1[k];
    acc = fmaf(px, W1[0 * 64 + k], acc);
    acc = fmaf(py, W1[1 * 64 + k], acc);
    acc = fmaf(pz, W1[2 * 64 + k], acc);
    acc = fmaf(ux, W1[3 * 64 + k], acc);
    acc = fmaf(uy, W1[4 * 64 + k], acc);
    acc = fmaf(uz, W1[5 * 64 + k], acc);
    B1[p * 64 + k] = f2bf(acc);
}

// ---------------------------------------------------------------------------
// K2 (R13-measured best): conv1 + k3 folded, M=64 tile (4 pts/iter), self
// rows amortized via Ssb (bf16).
// ---------------------------------------------------------------------------
#define PTS2 32
#define NG2 8
__global__ __launch_bounds__(256, 2)
void k2_conv1_mfma(const float* __restrict__ pos, const int* __restrict__ nbr,
                   const us* __restrict__ B1, const float* __restrict__ W1,
                   const float* __restrict__ g1, const float* __restrict__ bt1,
                   const float* __restrict__ m1, const float* __restrict__ v1,
                   const float* __restrict__ W2, const float* __restrict__ b2,
                   const float* __restrict__ W3, const float* __restrict__ b3,
                   us* __restrict__ A2) {
    __shared__ __align__(16) unsigned char Tl[2][64 * 128];
    __shared__ __align__(16) unsigned char Hl[32 * 256];
    __shared__ us Ssb[32 * 128];

    const int tid  = threadIdx.x;
    const int wv   = tid >> 6;
    const int lane = tid & 63;
    const int lgrp = lane >> 4;
    const int lmod = lane & 15;

    v8s Bf2[2][2];
    float b2c[2];
#pragma unroll
    for (int nt = 0; nt < 2; ++nt) {
        const int col = wv * 32 + nt * 16 + lmod;
        b2c[nt] = b2[col];
#pragma unroll
        for (int kt = 0; kt < 2; ++kt)
#pragma unroll
            for (int j = 0; j < 8; ++j)
                Bf2[nt][kt][j] = (short)f2bf(W2[(kt * 32 + lgrp * 8 + j) * 128 + col]);
    }
    const int ch = lane;
    const float w6 = W1[6 * 64 + ch], w7 = W1[7 * 64 + ch], w8 = W1[8 * 64 + ch];
    const float s1 = g1[ch] * rsqrtf(v1[ch] + BN_EPS);
    const float o1 = bt1[ch] - m1[ch] * s1;

    const int base = blockIdx.x * PTS2;

#pragma unroll
    for (int r = 0; r < 8; ++r) {
        const int pl = wv * 8 + r;
        const float bv = bf2f(B1[(size_t)(base + pl) * 64 + ch]);
        const float t = fmaf(fmaxf(bv, 0.f), s1, o1);
        int byte = pl * 128 + ch * 2;
        byte ^= (pl & 7) << 4;
        *(us*)(Tl[0] + byte) = f2bf(t);
    }
    __syncthreads();
    {
        f32x4 accS[2][2];
#pragma unroll
        for (int hf = 0; hf < 2; ++hf)
#pragma unroll
            for (int nt = 0; nt < 2; ++nt) accS[hf][nt] = f32x4{0.f, 0.f, 0.f, 0.f};
#pragma unroll
        for (int hf = 0; hf < 2; ++hf)
#pragma unroll
            for (int kt = 0; kt < 2; ++kt) {
                const int row = hf * 16 + lmod;
                int b0 = row * 128 + kt * 64 + lgrp * 16;
                b0 ^= (row & 7) << 4;
                const v8s a0 = *(const v8s*)(Tl[0] + b0);
#pragma unroll
                for (int nt = 0; nt < 2; ++nt)
                    accS[hf][nt] = __builtin_amdgcn_mfma_f32_16x16x32_bf16(a0, Bf2[nt][kt], accS[hf][nt], 0, 0, 0);
            }
#pragma unroll
        for (int hf = 0; hf < 2; ++hf)
#pragma unroll
            for (int nt = 0; nt < 2; ++nt)
#pragma unroll
                for (int reg = 0; reg < 4; ++reg)
                    Ssb[(hf * 16 + lgrp * 4 + reg) * 128 + wv * 32 + nt * 16 + lmod] =
                        f2bf(accS[hf][nt][reg]);
    }
    __syncthreads();

    {
        const int i0 = base + wv;
        const float cx = pos[i0 * 3 + 0], cy = pos[i0 * 3 + 1], cz = pos[i0 * 3 + 2];
#pragma unroll
        for (int m = 0; m < 16; ++m) {
            int idx = nbr[i0 * KNBR + m];
            idx = __builtin_amdgcn_readfirstlane(idx);
            const float bv = bf2f(B1[(size_t)idx * 64 + ch]);
            const float rx = pos[idx * 3 + 0] - cx;
            const float ry = pos[idx * 3 + 1] - cy;
            const float rz = pos[idx * 3 + 2] - cz;
            float pre = bv;
            pre = fmaf(rx, w6, pre); pre = fmaf(ry, w7, pre); pre = fmaf(rz, w8, pre);
            const float t = fmaf(fmaxf(pre, 0.f), s1, o1);
            const int row = wv * 16 + m;
            int byte = row * 128 + ch * 2;
            byte ^= (row & 7) << 4;
            *(us*)(Tl[0] + byte) = f2bf(t);
        }
    }
    __syncthreads();

    us aN[16];
    int idxN[16];
    float cNx = 0.f, cNy = 0.f, cNz = 0.f;
    for (int g = 0; g < NG2; ++g) {
        const int buf = g & 1;
        if (g < NG2 - 1) {
            const int iN = base + (g + 1) * 4 + wv;
            cNx = pos[iN * 3 + 0]; cNy = pos[iN * 3 + 1]; cNz = pos[iN * 3 + 2];
#pragma unroll
            for (int m = 0; m < 16; ++m) {
                int idx = nbr[iN * KNBR + m];
                idx = __builtin_amdgcn_readfirstlane(idx);
                idxN[m] = idx;
                aN[m] = B1[(size_t)idx * 64 + ch];
            }
        }
#pragma unroll
        for (int rb = 0; rb < 4; ++rb) {
            f32x4 acc[2];
            acc[0] = f32x4{0.f, 0.f, 0.f, 0.f};
            acc[1] = f32x4{0.f, 0.f, 0.f, 0.f};
#pragma unroll
            for (int kt = 0; kt < 2; ++kt) {
                const int row = rb * 16 + lmod;
                int b0 = row * 128 + kt * 64 + lgrp * 16;
                b0 ^= (row & 7) << 4;
                const v8s a0 = *(const v8s*)(Tl[buf] + b0);
#pragma unroll
                for (int nt = 0; nt < 2; ++nt)
                    acc[nt] = __builtin_amdgcn_mfma_f32_16x16x32_bf16(a0, Bf2[nt][kt], acc[nt], 0, 0, 0);
            }
            const int pl = g * 4 + rb;
#pragma unroll
            for (int nt = 0; nt < 2; ++nt) {
                float mv = fmaxf(fmaxf(acc[nt][0], acc[nt][1]),
                                 fmaxf(acc[nt][2], acc[nt][3]));
                mv = fmaxf(mv, __shfl_xor(mv, 16));
                mv = fmaxf(mv, __shfl_xor(mv, 32));
                const float ss = bf2f(Ssb[pl * 128 + wv * 32 + nt * 16 + lmod]);
                const float h = fmaxf(fmaxf(mv, ss) + b2c[nt], 0.f);
                if (lgrp == 0) {
                    int hb = pl * 256 + (wv * 32 + nt * 16 + lmod) * 2;
                    hb ^= (pl & 7) << 4;
                    *(us*)(Hl + hb) = f2bf(h);
                }
            }
        }
        if (g < NG2 - 1) {
#pragma unroll
            for (int m = 0; m < 16; ++m) {
                const int idx = idxN[m];
                const float rx = pos[idx * 3 + 0] - cNx;
                const float ry = pos[idx * 3 + 1] - cNy;
                const float rz = pos[idx * 3 + 2] - cNz;
                float pre = bf2f(aN[m]);
                pre = fmaf(rx, w6, pre); pre = fmaf(ry, w7, pre); pre = fmaf(rz, w8, pre);
                const float t = fmaf(fmaxf(pre, 0.f), s1, o1);
                const int row = wv * 16 + m;
                int byte = row * 128 + ch * 2;
                byte ^= (row & 7) << 4;
                *(us*)(Tl[buf ^ 1] + byte) = f2bf(t);
            }
        }
        __syncthreads();
    }

    v8s Wf3[2][4];
    float b3c[2];
#pragma unroll
    for (int nt = 0; nt < 2; ++nt) {
        const int col = wv * 32 + nt * 16 + lmod;
        b3c[nt] = b3[col];
#pragma unroll
        for (int kt = 0; kt < 4; ++kt)
#pragma unroll
            for (int j = 0; j < 8; ++j)
                Wf3[nt][kt][j] = (short)f2bf(W3[(kt * 32 + lgrp * 8 + j) * 128 + col]);
    }
    f32x4 accA[2][2];
#pragma unroll
    for (int mt = 0; mt < 2; ++mt)
#pragma unroll
        for (int nt = 0; nt < 2; ++nt) accA[mt][nt] = f32x4{0.f, 0.f, 0.f, 0.f};
#pragma unroll
    for (int kt = 0; kt < 4; ++kt) {
#pragma unroll
        for (int mt = 0; mt < 2; ++mt) {
            int ba = (mt * 16 + lmod) * 256 + kt * 64 + lgrp * 16;
            ba ^= (lmod & 7) << 4;
            const v8s aH = *(const v8s*)(Hl + ba);
#pragma unroll
            for (int nt = 0; nt < 2; ++nt)
                accA[mt][nt] = __builtin_amdgcn_mfma_f32_16x16x32_bf16(aH, Wf3[nt][kt], accA[mt][nt], 0, 0, 0);
        }
    }
#pragma unroll
    for (int mt = 0; mt < 2; ++mt)
#pragma unroll
        for (int nt = 0; nt < 2; ++nt)
#pragma unroll
            for (int reg = 0; reg < 4; ++reg) {
                const int row = base + mt * 16 + lgrp * 4 + reg;
                const int col = wv * 32 + nt * 16 + lmod;
                A2[(size_t)row * 128 + col] = f2bf(accA[mt][nt][reg] + b3c[nt]);
            }
}

// ---------------------------------------------------------------------------
// K4 (R11-measured best, 173 us): point-serial, depth-2 prefetch, self rows
// amortized via Ssb (bf16, R12-verified); classifier partials -> Z; k5 does
// log_softmax. LDS 24KB (was 40KB).
// ---------------------------------------------------------------------------
#define PTS4 32
__global__ __launch_bounds__(256, 2)
void k4_conv2_mfma(const float* __restrict__ pos, const int* __restrict__ nbr,
                   const us* __restrict__ A2, const float* __restrict__ W3,
                   const float* __restrict__ g2, const float* __restrict__ bt2,
                   const float* __restrict__ m2, const float* __restrict__ v2,
                   const float* __restrict__ W4, const float* __restrict__ b4,
                   const float* __restrict__ Wc,
                   float* __restrict__ Z) {
    __shared__ __align__(16) unsigned char Tl[2][16 * 256];  // 4KB each
    __shared__ us Ssb[32 * 256];                             // 16KB

    const int tid  = threadIdx.x;
    const int wv   = tid >> 6;
    const int lane = tid & 63;
    const int lgrp = lane >> 4;
    const int lmod = lane & 15;

    v8s Bf[4][4];
#pragma unroll
    for (int nt = 0; nt < 4; ++nt) {
        const int col = wv * 64 + nt * 16 + lmod;
#pragma unroll
        for (int kt = 0; kt < 4; ++kt)
#pragma unroll
            for (int j = 0; j < 8; ++j)
                Bf[nt][kt][j] = (short)f2bf(W4[(kt * 32 + lgrp * 8 + j) * 256 + col]);
    }
    float wcls[4][8]; float b4c[4];
#pragma unroll
    for (int nt = 0; nt < 4; ++nt) {
        const int col = wv * 64 + nt * 16 + lmod;
        b4c[nt] = b4[col];
#pragma unroll
        for (int c = 0; c < 8; ++c) wcls[nt][c] = Wc[col * 8 + c];
    }
    const int ch0 = lane * 2;
    const float bw0a = W3[128 * 128 + ch0],     bw1a = W3[129 * 128 + ch0],     bw2a = W3[130 * 128 + ch0];
    const float bw0b = W3[128 * 128 + ch0 + 1], bw1b = W3[129 * 128 + ch0 + 1], bw2b = W3[130 * 128 + ch0 + 1];
    const float sa = g2[ch0] * rsqrtf(v2[ch0] + BN_EPS);
    const float oa = bt2[ch0] - m2[ch0] * sa;
    const float sb = g2[ch0 + 1] * rsqrtf(v2[ch0 + 1] + BN_EPS);
    const float ob = bt2[ch0 + 1] - m2[ch0 + 1] * sb;

    const int base = blockIdx.x * PTS4;

    // ---- prologue A (wave-split): self rows, wave wv covers pl [wv*8, wv*8+8) ----
#pragma unroll
    for (int r = 0; r < 8; ++r) {
        const int pl = wv * 8 + r;
        const unsigned int a = *(const unsigned int*)&A2[(size_t)(base + pl) * 128 + ch0];
        const float ta = fmaf(fmaxf(bflo(a), 0.f), sa, oa);
        const float tb = fmaf(fmaxf(bfhi(a), 0.f), sb, ob);
        const unsigned int w = (unsigned int)f2bf(ta) | ((unsigned int)f2bf(tb) << 16);
        const int row = pl & 15;
        int byte = row * 256 + ch0 * 2;
        byte ^= (row & 7) << 4;
        *(unsigned int*)(Tl[pl >> 4] + byte) = w;
    }
    __syncthreads();
    // ---- prologue B: Ssb = self @ W4 (bf16) ----
    {
        f32x4 accS[2][4];
#pragma unroll
        for (int hf = 0; hf < 2; ++hf)
#pragma unroll
            for (int nt = 0; nt < 4; ++nt) accS[hf][nt] = f32x4{0.f, 0.f, 0.f, 0.f};
#pragma unroll
        for (int hf = 0; hf < 2; ++hf)
#pragma unroll
            for (int kt = 0; kt < 4; ++kt) {
                int b0 = lmod * 256 + kt * 64 + lgrp * 16;
                b0 ^= (lmod & 7) << 4;
                const v8s a0 = *(const v8s*)(Tl[hf] + b0);
#pragma unroll
                for (int nt = 0; nt < 4; ++nt)
                    accS[hf][nt] = __builtin_amdgcn_mfma_f32_16x16x32_bf16(a0, Bf[nt][kt], accS[hf][nt], 0, 0, 0);
            }
#pragma unroll
        for (int hf = 0; hf < 2; ++hf)
#pragma unroll
            for (int nt = 0; nt < 4; ++nt)
#pragma unroll
                for (int reg = 0; reg < 4; ++reg)
                    Ssb[(hf * 16 + lgrp * 4 + reg) * 256 + wv * 64 + nt * 16 + lmod] =
                        f2bf(accS[hf][nt][reg]);
    }
    __syncthreads();

    // ---- build T p=0 (16 neighbor rows); prefetch p=1 ----
    {
        const int i = base;
        const float cx = pos[i * 3 + 0], cy = pos[i * 3 + 1], cz = pos[i * 3 + 2];
#pragma unroll
        for (int it = 0; it < 4; ++it) {
            const int m = it * 4 + wv;                 // 0..15
            const int idx = nbr[i * KNBR + m];
            const unsigned int a = *(const unsigned int*)&A2[(size_t)idx * 128 + ch0];
            const float rx = pos[idx * 3 + 0] - cx;
            const float ry = pos[idx * 3 + 1] - cy;
            const float rz = pos[idx * 3 + 2] - cz;
            float pa = bflo(a);
            pa = fmaf(rx, bw0a, pa); pa = fmaf(ry, bw1a, pa); pa = fmaf(rz, bw2a, pa);
            float pb = bfhi(a);
            pb = fmaf(rx, bw0b, pb); pb = fmaf(ry, bw1b, pb); pb = fmaf(rz, bw2b, pb);
            const float ta = fmaf(fmaxf(pa, 0.f), sa, oa);
            const float tb = fmaf(fmaxf(pb, 0.f), sb, ob);
            const unsigned int w = (unsigned int)f2bf(ta) | ((unsigned int)f2bf(tb) << 16);
            int byte = m * 256 + ch0 * 2;
            byte ^= (m & 7) << 4;
            *(unsigned int*)(Tl[0] + byte) = w;
        }
    }
    unsigned int aCur[4], aNxt[4];
    float pCx[4], pCy[4], pCz[4], pNx[4], pNy[4], pNz[4];
#pragma unroll
    for (int it = 0; it < 4; ++it) { aCur[it] = 0u; aNxt[it] = 0u; pCx[it]=pCy[it]=pCz[it]=pNx[it]=pNy[it]=pNz[it]=0.f; }
    {
        const int in_ = base + 1;
#pragma unroll
        for (int it = 0; it < 4; ++it) {
            const int m = it * 4 + wv;
            const int idx = nbr[in_ * KNBR + m];
            aCur[it] = *(const unsigned int*)&A2[(size_t)idx * 128 + ch0];
            pCx[it] = pos[idx * 3 + 0]; pCy[it] = pos[idx * 3 + 1]; pCz[it] = pos[idx * 3 + 2];
        }
    }
    __syncthreads();

    for (int p = 0; p < PTS4; ++p) {
        const int buf = p & 1;
        if (p < PTS4 - 2) {
            const int in2 = base + p + 2;
#pragma unroll
            for (int it = 0; it < 4; ++it) {
                const int m = it * 4 + wv;
                const int idx = nbr[in2 * KNBR + m];
                aNxt[it] = *(const unsigned int*)&A2[(size_t)idx * 128 + ch0];
                pNx[it] = pos[idx * 3 + 0]; pNy[it] = pos[idx * 3 + 1]; pNz[it] = pos[idx * 3 + 2];
            }
        }
        // ---- GEMM (16 neighbor rows) ----
        f32x4 acc0[4];
#pragma unroll
        for (int nt = 0; nt < 4; ++nt) acc0[nt] = f32x4{0.f, 0.f, 0.f, 0.f};
#pragma unroll
        for (int kt = 0; kt < 4; ++kt) {
            int b0 = lmod * 256 + kt * 64 + lgrp * 16;
            b0 ^= (lmod & 7) << 4;
            const v8s a0 = *(const v8s*)(Tl[buf] + b0);
#pragma unroll
            for (int nt = 0; nt < 4; ++nt)
                acc0[nt] = __builtin_amdgcn_mfma_f32_16x16x32_bf16(a0, Bf[nt][kt], acc0[nt], 0, 0, 0);
        }
        // ---- epilogue: max + self + classifier partials -> Z ----
        float part[8];
#pragma unroll
        for (int c = 0; c < 8; ++c) part[c] = 0.f;
#pragma unroll
        for (int nt = 0; nt < 4; ++nt) {
            float mv = fmaxf(fmaxf(acc0[nt][0], acc0[nt][1]),
                             fmaxf(acc0[nt][2], acc0[nt][3]));
            mv = fmaxf(mv, __shfl_xor(mv, 16));
            mv = fmaxf(mv, __shfl_xor(mv, 32));
            const float ss = bf2f(Ssb[p * 256 + wv * 64 + nt * 16 + lmod]);
            const float h = fmaxf(fmaxf(mv, ss) + b4c[nt], 0.f);
#pragma unroll
            for (int c = 0; c < 8; ++c) part[c] = fmaf(h, wcls[nt][c], part[c]);
        }
#pragma unroll
        for (int c = 0; c < 8; ++c) {
            part[c] += __shfl_xor(part[c], 1);
            part[c] += __shfl_xor(part[c], 2);
            part[c] += __shfl_xor(part[c], 4);
            part[c] += __shfl_xor(part[c], 8);
        }
        if (lane == 0) {
#pragma unroll
            for (int c = 0; c < 8; ++c)
                Z[(size_t)(base + p) * 32 + wv * 8 + c] = part[c];
        }
        // ---- build T p+1 from aCur ----
        if (p < PTS4 - 1) {
            const int in_ = base + p + 1;
            const float ccx = pos[in_ * 3 + 0], ccy = pos[in_ * 3 + 1], ccz = pos[in_ * 3 + 2];
#pragma unroll
            for (int it = 0; it < 4; ++it) {
                const int m = it * 4 + wv;
                const float rx = pCx[it] - ccx, ry = pCy[it] - ccy, rz = pCz[it] - ccz;
                float pa = bflo(aCur[it]);
                pa = fmaf(rx, bw0a, pa); pa = fmaf(ry, bw1a, pa); pa = fmaf(rz, bw2a, pa);
                float pb = bfhi(aCur[it]);
                pb = fmaf(rx, bw0b, pb); pb = fmaf(ry, bw1b, pb); pb = fmaf(rz, bw2b, pb);
                const float ta = fmaf(fmaxf(pa, 0.f), sa, oa);
                const float tb = fmaf(fmaxf(pb, 0.f), sb, ob);
                const unsigned int w = (unsigned int)f2bf(ta) | ((unsigned int)f2bf(tb) << 16);
                int byte = m * 256 + ch0 * 2;
                byte ^= (m & 7) << 4;
                *(unsigned int*)(Tl[buf ^ 1] + byte) = w;
            }
        }
        __syncthreads();
#pragma unroll
        for (int it = 0; it < 4; ++it) {
            aCur[it] = aNxt[it];
            pCx[it] = pNx[it]; pCy[it] = pNy[it]; pCz[it] = pNz[it];
        }
    }
}

// ---------------------------------------------------------------------------
// K5: out[i] = log_softmax( sum_w Z[i][w] + bc )
// ---------------------------------------------------------------------------
__global__ __launch_bounds__(256, 4)
void k5_softmax(const float* __restrict__ Z, const float* __restrict__ bc,
                float* __restrict__ out) {
    const int i = blockIdx.x * 256 + threadIdx.x;
    if (i >= NPTS) return;
    float z[8];
#pragma unroll
    for (int c = 0; c < 8; ++c) z[c] = bc[c];
#pragma unroll
    for (int w = 0; w < 4; ++w) {
        const float4 a = *(const float4*)&Z[(size_t)i * 32 + w * 8 + 0];
        const float4 b = *(const float4*)&Z[(size_t)i * 32 + w * 8 + 4];
        z[0] += a.x; z[1] += a.y; z[2] += a.z; z[3] += a.w;
        z[4] += b.x; z[5] += b.y; z[6] += b.z; z[7] += b.w;
    }
    float mz = z[0];
#pragma unroll
    for (int c = 1; c < 8; ++c) mz = fmaxf(mz, z[c]);
    float se = 0.f;
#pragma unroll
    for (int c = 0; c < 8; ++c) se += expf(z[c] - mz);
    const float lse = mz + logf(se);
#pragma unroll
    for (int c = 0; c < 8; ++c) out[(size_t)i * 8 + c] = z[c] - lse;
}

extern "C" void kernel_launch(void* const* d_in, const int* in_sizes, int n_in,
                              void* d_out, int out_size, void* d_ws, size_t ws_size,
                              hipStream_t stream) {
    const float* pos = (const float*)d_in[0];
    const int*   nbr = (const int*)d_in[1];
    const float* W1  = (const float*)d_in[2];
    const float* b1  = (const float*)d_in[3];
    const float* g1  = (const float*)d_in[4];
    const float* bt1 = (const float*)d_in[5];
    const float* m1  = (const float*)d_in[6];
    const float* v1  = (const float*)d_in[7];
    const float* W2  = (const float*)d_in[8];
    const float* b2  = (const float*)d_in[9];
    const float* W3  = (const float*)d_in[10];
    const float* b3  = (const float*)d_in[11];
    const float* g2  = (const float*)d_in[12];
    const float* bt2 = (const float*)d_in[13];
    const float* m2  = (const float*)d_in[14];
    const float* v2  = (const float*)d_in[15];
    const float* W4  = (const float*)d_in[16];
    const float* b4  = (const float*)d_in[17];
    const float* Wc  = (const float*)d_in[18];
    const float* bc  = (const float*)d_in[19];
    float* out = (float*)d_out;

    us* B1   = (us*)d_ws;                             // 40000*64*2  =  5.12 MB
    us* A2   = B1 + (size_t)NPTS * 64;                // 40000*128*2 = 10.24 MB
    float* Z = (float*)(A2 + (size_t)NPTS * 128);     // 40000*32*4  =  5.12 MB

    k1_b1<<<NPTS / 4, 256, 0, stream>>>(pos, nbr, W1, b1, B1);
    k2_conv1_mfma<<<NPTS / PTS2, 256, 0, stream>>>(pos, nbr, B1, W1, g1, bt1, m1, v1,
                                                   W2, b2, W3, b3, A2);
    k4_conv2_mfma<<<NPTS / PTS4, 256, 0, stream>>>(pos, nbr, A2, W3, g2, bt2, m2, v2,
                                                   W4, b4, Wc, Z);
    k5_softmax<<<(NPTS + 255) / 256, 256, 0, stream>>>(Z, bc, out);
}